// Round 12
// baseline (101.854 us; speedup 1.0000x reference)
//
#include <hip/hip_runtime.h>
#include <cfloat>

#define NB 4096           // nodes per batch
#define FD 64             // feature dim
#define QPB 4             // queries per block (one per wave)
#define LRELU_ALPHA 0.2f
#define CCAP 96           // per-query candidate cap (E[cands] ~ 30 w/ slack)

// prep: blocks 0..511: Wh = x@W, f1 = Wh@a[:64], f2 = Wh@a[64:]
//       blocks 512..543: pq[i] = (x,y,z, 0.5*|p|^2 fast)  (dense 16B stream
//       for the gat screen; exact path still reads raw pos)
__global__ __launch_bounds__(256) void prep_kernel(
    const float* __restrict__ x, const float* __restrict__ pos,
    const float* __restrict__ W, const float* __restrict__ a,
    float* __restrict__ Wh, float* __restrict__ f1, float* __restrict__ f2,
    float4* __restrict__ pq)
{
    const int tid = threadIdx.x;
    if (blockIdx.x >= 512) {
        const int i = (blockIdx.x - 512) * 256 + tid;   // 0..8191
        const float px = pos[i * 3 + 0];
        const float py = pos[i * 3 + 1];
        const float pz = pos[i * 3 + 2];
        pq[i] = make_float4(px, py, pz, 0.5f * fmaf(pz, pz, fmaf(py, py, px * px)));
        return;
    }
    __shared__ float sW[FD * FD];
    #pragma unroll
    for (int t = 0; t < 16; ++t) sW[tid + t * 256] = W[tid + t * 256];
    __syncthreads();
    const int lane = tid & 63, wave = tid >> 6;
    const float a1v = a[lane], a2v = a[FD + lane];
    const int rbase = blockIdx.x * 16 + wave * 4;
    #pragma unroll
    for (int j = 0; j < 4; j += 2) {                 // 2 rows in flight (ILP)
        const int r0 = rbase + j, r1 = rbase + j + 1;
        const float xv0 = x[((size_t)r0 << 6) + lane];
        const float xv1 = x[((size_t)r1 << 6) + lane];
        float acc0 = 0.f, acc1 = 0.f;
        #pragma unroll
        for (int i = 0; i < FD; ++i) {
            const float wv = sW[i * FD + lane];
            acc0 = fmaf(__shfl(xv0, i, 64), wv, acc0);
            acc1 = fmaf(__shfl(xv1, i, 64), wv, acc1);
        }
        Wh[((size_t)r0 << 6) + lane] = acc0;
        Wh[((size_t)r1 << 6) + lane] = acc1;
        float s10 = acc0 * a1v, s20 = acc0 * a2v;
        float s11 = acc1 * a1v, s21 = acc1 * a2v;
        #pragma unroll
        for (int off = 32; off > 0; off >>= 1) {
            s10 += __shfl_down(s10, off, 64);
            s20 += __shfl_down(s20, off, 64);
            s11 += __shfl_down(s11, off, 64);
            s21 += __shfl_down(s21, off, 64);
        }
        if (lane == 0) { f1[r0] = s10; f2[r0] = s20; f1[r1] = s11; f2[r1] = s21; }
    }
}

// 4 queries/block. Node stream = pq float4, stride-256 interleave: each
// wave-load is 64x16B = 1KB dense (8 lines/instr) vs 12B-stride scalar's
// 6 lines per 256B (R11's hidden L1-service floor). Screen metric
// e = 0.5|p|^2 - q.p (order == d2 order per query; 4 VALU/pair). Pass 1:
// per-thread e-min + per-wave bitonic of 64 disjoint-group minima ->
// provable bound T (sorted[k] >= global (k+1)-th smallest: subset order
// statistic). Pass 2: append-index-only, slack >> all fast-vs-rn rounding
// gaps -> candidates ⊇ exact top-(k+1). Select: exact rn-op-order d2 (raw
// pos) on ~30 candidates -> u64 (d2,idx) rank = bit-identical jax.lax.top_k
// stable order; rank 0 dropped (= ref col 0). Phase B: wave-private softmax
// + 20 coalesced Wh-row fmas. launch_bounds(256,8): VGPR<64 (R10 lesson).
__global__ __launch_bounds__(256, 8) void gat_fused(
    const float* __restrict__ pos, const float4* __restrict__ pq,
    const float* __restrict__ Wh,
    const float* __restrict__ f1, const float* __restrict__ f2,
    const float* __restrict__ Wp, const float* __restrict__ bp,
    const int* __restrict__ kptr, float* __restrict__ out)
{
    __shared__ union Pool {
        float tmin[QPB * 256];                         // phase A1 (4 KB)
        struct {
            unsigned long long pkbuf[QPB][CCAP];       // select (3 KB)
            int cidx[QPB][CCAP];                       // pass 2 (1.5 KB)
        } s;
    } pool;
    __shared__ float4 sq[QPB];                         // qx,qy,qz,|q|^2 (rn)
    __shared__ float sT[QPB];
    __shared__ unsigned int cnt[QPB];
    __shared__ int idx21[QPB][24];

    const int tid = threadIdx.x;
    const int lane = tid & 63, wave = tid >> 6;
    const int qbase = blockIdx.x * QPB;                // row of query 0
    const int b = qbase >> 12;                         // same batch (4096%4==0)
    const float* posb = pos + (size_t)b * NB * 3;
    const float4* pq4 = pq + ((size_t)b << 12);
    const int k = *kptr;                               // 20

    if (tid < QPB) {
        const int nq = (qbase + tid) & (NB - 1);
        const float ax = posb[nq * 3 + 0], ay = posb[nq * 3 + 1], az = posb[nq * 3 + 2];
        const float sr = __fadd_rn(__fadd_rn(__fmul_rn(ax, ax), __fmul_rn(ay, ay)),
                                   __fmul_rn(az, az));
        sq[tid] = make_float4(ax, ay, az, sr);
        cnt[tid] = 0;
    }
    // safety net: in-bounds defaults (provably overwritten; avoids OOB if a
    // corner ever yields cn<k+1)
    if (lane < 24) idx21[wave][lane] = (qbase + wave) & (NB - 1);
    __syncthreads();                                   // B1

    const float4 q0 = sq[0], q1 = sq[1], q2 = sq[2], q3 = sq[3];

    // pass 1: fast screen, dense float4 node stream
    float f0 = FLT_MAX, f1m = FLT_MAX, f2m = FLT_MAX, f3m = FLT_MAX;
    #pragma unroll 4
    for (int t = 0; t < 16; ++t) {
        const float4 p = pq4[t * 256 + tid];
        float d;
        d = p.w - fmaf(q0.x, p.x, fmaf(q0.y, p.y, q0.z * p.z));
        f0 = fminf(f0, d);
        d = p.w - fmaf(q1.x, p.x, fmaf(q1.y, p.y, q1.z * p.z));
        f1m = fminf(f1m, d);
        d = p.w - fmaf(q2.x, p.x, fmaf(q2.y, p.y, q2.z * p.z));
        f2m = fminf(f2m, d);
        d = p.w - fmaf(q3.x, p.x, fmaf(q3.y, p.y, q3.z * p.z));
        f3m = fminf(f3m, d);
    }
    pool.tmin[0 * 256 + tid] = f0;  pool.tmin[1 * 256 + tid] = f1m;
    pool.tmin[2 * 256 + tid] = f2m; pool.tmin[3 * 256 + tid] = f3m;
    __syncthreads();                                   // B2

    // wave w: bitonic-sort 64 disjoint-group e-minima of query w
    float v = fminf(fminf(pool.tmin[wave * 256 + lane],
                          pool.tmin[wave * 256 + 64 + lane]),
                    fminf(pool.tmin[wave * 256 + 128 + lane],
                          pool.tmin[wave * 256 + 192 + lane]));
    #pragma unroll
    for (int kk2 = 2; kk2 <= 64; kk2 <<= 1) {
        #pragma unroll
        for (int j = kk2 >> 1; j > 0; j >>= 1) {
            const float o = __shfl_xor(v, j, 64);
            const bool keepMin = (((lane & j) == 0) == ((lane & kk2) == 0));
            v = keepMin ? fminf(v, o) : fmaxf(v, o);
        }
    }
    const float Tq = __shfl(v, k, 64);                 // all lanes execute (R8 lesson)
    if (lane == 0) sT[wave] = Tq;
    __syncthreads();                                   // B3 (tmin dead -> s.*)

    // slack (e-space): 1e-2 + 1e-3|T| >> all fast-vs-rn gaps (~1e-6)
    const float Ts0 = sT[0] + 1e-2f + 1e-3f * fabsf(sT[0]);
    const float Ts1 = sT[1] + 1e-2f + 1e-3f * fabsf(sT[1]);
    const float Ts2 = sT[2] + 1e-2f + 1e-3f * fabsf(sT[2]);
    const float Ts3 = sT[3] + 1e-2f + 1e-3f * fabsf(sT[3]);

    // pass 2: re-screen (same dense stream); append index only
    #pragma unroll 4
    for (int t = 0; t < 16; ++t) {
        const int m = t * 256 + tid;
        const float4 p = pq4[m];
        float d;
        d = p.w - fmaf(q0.x, p.x, fmaf(q0.y, p.y, q0.z * p.z));
        if (d <= Ts0) {
            const unsigned int pp = atomicAdd(&cnt[0], 1u);
            if (pp < CCAP) pool.s.cidx[0][pp] = m;
        }
        d = p.w - fmaf(q1.x, p.x, fmaf(q1.y, p.y, q1.z * p.z));
        if (d <= Ts1) {
            const unsigned int pp = atomicAdd(&cnt[1], 1u);
            if (pp < CCAP) pool.s.cidx[1][pp] = m;
        }
        d = p.w - fmaf(q2.x, p.x, fmaf(q2.y, p.y, q2.z * p.z));
        if (d <= Ts2) {
            const unsigned int pp = atomicAdd(&cnt[2], 1u);
            if (pp < CCAP) pool.s.cidx[2][pp] = m;
        }
        d = p.w - fmaf(q3.x, p.x, fmaf(q3.y, p.y, q3.z * p.z));
        if (d <= Ts3) {
            const unsigned int pp = atomicAdd(&cnt[3], 1u);
            if (pp < CCAP) pool.s.cidx[3][pp] = m;
        }
    }
    __syncthreads();                                   // B4 — last barrier

    // select (wave w <- query w): exact rn-op-order d2 (raw pos), u64 rank
    const float4 qq = sq[wave];
    const int cn0 = (int)cnt[wave];
    const int cn = cn0 < CCAP ? cn0 : CCAP;
    for (int e = lane; e < cn; e += 64) {
        const int m = pool.s.cidx[wave][e];
        const float px = posb[m * 3 + 0];
        const float py = posb[m * 3 + 1];
        const float pz = posb[m * 3 + 2];
        const float sqm = __fadd_rn(__fadd_rn(__fmul_rn(px, px), __fmul_rn(py, py)),
                                    __fmul_rn(pz, pz));
        const float dot = __fadd_rn(__fadd_rn(__fmul_rn(qq.x, px), __fmul_rn(qq.y, py)),
                                    __fmul_rn(qq.z, pz));
        const float d2 = __fsub_rn(__fadd_rn(qq.w, sqm), __fmul_rn(2.0f, dot));
        const unsigned int u = __float_as_uint(d2);
        const unsigned int kk = u ^ ((unsigned int)((int)u >> 31) | 0x80000000u);
        pool.s.pkbuf[wave][e] = ((unsigned long long)kk << 12) | (unsigned int)m;
    }
    for (int e = lane; e < cn; e += 64) {
        const unsigned long long xv = pool.s.pkbuf[wave][e];
        int r = 0;
        for (int j = 0; j < cn; ++j) r += (pool.s.pkbuf[wave][j] < xv);
        if (r <= k) idx21[wave][r] = (int)(xv & 0xFFFu);
    }
    // wave-private LDS RAW: in-order per wave + compiler lgkmcnt, no barrier

    // phase B (wave-private): scores, softmax, Wh-row gather
    const int row = qbase + wave;
    const bool valid = (lane >= 1 && lane <= k);
    const int nbr = valid ? idx21[wave][lane] : 0;
    const float f1v = f1[row];
    float e = -FLT_MAX;
    if (valid) {
        e = f1v + f2[(b << 12) + nbr];
        e = e > 0.f ? e : LRELU_ALPHA * e;
    }
    float mx = e;
    #pragma unroll
    for (int off = 32; off > 0; off >>= 1) mx = fmaxf(mx, __shfl_xor(mx, off, 64));
    const float ex = valid ? __expf(e - mx) : 0.f;
    float Z = ex;
    #pragma unroll
    for (int off = 32; off > 0; off >>= 1) Z += __shfl_xor(Z, off, 64);
    const float attn = ex / Z;                         // lane t holds attn_t

    const float* whb = Wh + (((size_t)b << 12) << 6);
    float h = 0.f;
    #pragma unroll 4
    for (int t = 1; t <= k; ++t) {
        const int nb_ = __shfl(nbr, t, 64);
        const float s = __shfl(attn, t, 64);
        h = fmaf(s, whb[((size_t)nb_ << 6) + lane], h);
    }

    const float pv = fmaf(qq.x, Wp[0 * FD + lane],
                     fmaf(qq.y, Wp[1 * FD + lane],
                     fmaf(qq.z, Wp[2 * FD + lane], bp[lane])));
    h += pv > 0.f ? pv : 0.f;
    out[((size_t)row << 6) + lane] = h > 0.f ? h : expm1f(h);
}

extern "C" void kernel_launch(void* const* d_in, const int* in_sizes, int n_in,
                              void* d_out, int out_size, void* d_ws, size_t ws_size,
                              hipStream_t stream) {
    const float* x   = (const float*)d_in[0];
    const float* pos = (const float*)d_in[1];
    const float* W   = (const float*)d_in[2];
    const float* a   = (const float*)d_in[3];
    const float* Wp  = (const float*)d_in[4];
    const float* bp  = (const float*)d_in[5];
    const int*   kp  = (const int*)d_in[6];

    float* ws = (float*)d_ws;
    float*  Wh = ws;                        // 8192*64 = 524288
    float*  f1 = Wh + 524288;               // 8192
    float*  f2 = f1 + 8192;                 // 8192
    float4* pq = (float4*)(f2 + 8192);      // 8192 float4 (16B-aligned)
    float*  out = (float*)d_out;

    prep_kernel<<<544, 256, 0, stream>>>(x, pos, W, a, Wh, f1, f2, pq);
    gat_fused<<<(NB * 2) / QPB, 256, 0, stream>>>(pos, pq, Wh, f1, f2, Wp, bp, kp, out);
}